// Round 8
// baseline (531.811 us; speedup 1.0000x reference)
//
#include <hip/hip_runtime.h>
#include <math.h>

#define BN    2456
#define LSEQ  12
#define DM    128
#define NODES 307
#define MROWS 29472   // BN * LSEQ

typedef __bf16 bfx8 __attribute__((ext_vector_type(8)));
typedef float  f32x4 __attribute__((ext_vector_type(4)));

#define MFMA16(a, b, c) __builtin_amdgcn_mfma_f32_16x16x32_bf16(a, b, c, 0, 0, 0)

__device__ __forceinline__ float fsilu(float v)     { return v / (1.0f + __expf(-v)); }
__device__ __forceinline__ float fsoftplus(float x) { return fmaxf(x, 0.f) + __logf(1.0f + __expf(-fabsf(x))); }

// ---------------- K0: convert weights to bf16 once per call ----------------
__global__ __launch_bounds__(256)
void k_convert(const float* __restrict__ in_w, const float* __restrict__ x_w,
               const float* __restrict__ out_w, const float* __restrict__ dt_w,
               const float* __restrict__ graph,
               __bf16* __restrict__ in_w_bf, __bf16* __restrict__ x_w_bf,
               __bf16* __restrict__ out_w_bf, __bf16* __restrict__ dtw_bf,
               __bf16* __restrict__ graphT_bf) {
    int idx = blockIdx.x * 256 + threadIdx.x;
    if (idx < 131072) { in_w_bf[idx] = (__bf16)in_w[idx]; return; }
    idx -= 131072;
    if (idx < 98304) { x_w_bf[idx] = (__bf16)x_w[idx]; return; }
    idx -= 98304;
    if (idx < 65536) { out_w_bf[idx] = (__bf16)out_w[idx]; return; }
    idx -= 65536;
    if (idx < 65536) { dtw_bf[idx] = (__bf16)dt_w[idx]; return; }
    idx -= 65536;
    if (idx < 1572864) {
        int bl = idx >> 14, r = idx & 16383;
        int d = r >> 7, a = r & 127;
        graphT_bf[(size_t)bl * 16384 + a * 128 + d] = (__bf16)graph[idx];
    }
}

// ---------------- per-half (128-thread) reductions inside a 256-thread block ----------------
template <int N>
__device__ __forceinline__ void red_sum_h(float* v, float* sred, int htid, int half) {
#pragma unroll
    for (int off = 32; off; off >>= 1)
#pragma unroll
        for (int i = 0; i < N; ++i) v[i] += __shfl_xor(v[i], off, 64);
    if ((htid & 63) == 0) {
#pragma unroll
        for (int i = 0; i < N; ++i) sred[half * 2 * N + (htid >> 6) * N + i] = v[i];
    }
    __syncthreads();
#pragma unroll
    for (int i = 0; i < N; ++i) v[i] = sred[half * 2 * N + i] + sred[half * 2 * N + N + i];
    __syncthreads();
}

template <int N>
__device__ __forceinline__ void red_max_h(float* v, float* sred, int htid, int half) {
#pragma unroll
    for (int off = 32; off; off >>= 1)
#pragma unroll
        for (int i = 0; i < N; ++i) v[i] = fmaxf(v[i], __shfl_xor(v[i], off, 64));
    if ((htid & 63) == 0) {
#pragma unroll
        for (int i = 0; i < N; ++i) sred[half * 2 * N + (htid >> 6) * N + i] = v[i];
    }
    __syncthreads();
#pragma unroll
    for (int i = 0; i < N; ++i) v[i] = fmaxf(sred[half * 2 * N + i], sred[half * 2 * N + N + i]);
    __syncthreads();
}

// ---------------- K1: rmsnorm + freq + in_proj + silu + x_proj + dt_proj ----------------
// grid (1228) x 256. block = 2 bn-rows (24 M-rows). half = row within block.
__global__ __launch_bounds__(256)
void k_fiq(const float* __restrict__ xprev, const float* __restrict__ norm_w,
           const float* __restrict__ fw_r, const float* __restrict__ fw_i,
           const __bf16* __restrict__ in_w_bf, const float* __restrict__ in_b,
           const __bf16* __restrict__ x_w_bf, const __bf16* __restrict__ dtw_bf,
           const float* __restrict__ dt_b,
           __bf16* __restrict__ xfq_bf, __bf16* __restrict__ xs_bf,
           __bf16* __restrict__ sz_bf, float* __restrict__ bcf32,
           __bf16* __restrict__ dpf, __bf16* __restrict__ delta_bf, int e) {
    __shared__ __bf16 sxn[32 * 136];
    __shared__ __bf16 sxs[32 * 136];
    __shared__ __bf16 sdel[32 * 40];
    __shared__ float s_c[24], s_s[24], s_wr[133], s_wi[133];
    __shared__ float sred[48];
    const int tid = threadIdx.x;
    const int half = tid >> 7, htid = tid & 127;
    const int row = blockIdx.x * 2 + half;
    const int m0g = blockIdx.x * 24;

    if (tid < 24) {
        float sv, cv;
        __sincosf(6.283185307179586f * (float)tid / 24.0f, &sv, &cv);
        s_c[tid] = cv; s_s[tid] = sv;
    }
    for (int i = tid; i < 133; i += 256) { s_wr[i] = fw_r[e * 133 + i]; s_wi[i] = fw_i[e * 133 + i]; }
    // zero pad rows 24..31
    for (int i = tid; i < 8 * 136; i += 256) { sxn[24 * 136 + i] = (__bf16)0.f; sxs[24 * 136 + i] = (__bf16)0.f; }
    for (int i = tid; i < 8 * 40; i += 256) sdel[24 * 40 + i] = (__bf16)0.f;

    // ---- phase A: rmsnorm + freq gating (d = htid, per-half row) ----
    const float* xp = xprev + (size_t)row * 1536 + htid;
    float xv[12], v[12];
#pragma unroll
    for (int l = 0; l < 12; ++l) { xv[l] = xp[l * 128]; v[l] = xv[l] * xv[l]; }
    __syncthreads();
    red_sum_h<12>(v, sred, htid, half);

    const float nrmw = norm_w[e * DM + htid];
    float xnr[12];
#pragma unroll
    for (int l = 0; l < 12; ++l)
        xnr[l] = xv[l] * rsqrtf(v[l] * (1.0f / 128.0f) + 1e-5f) * nrmw;
#pragma unroll
    for (int l = 0; l < 12; ++l)
        sxn[(half * 12 + l) * 136 + htid] = (__bf16)xnr[l];

    // DFT n=24 padded, 13 bins; f (n=12) = fp at even bins
    float fpr[13], fpi[13];
#pragma unroll
    for (int k = 0; k < 13; ++k) { fpr[k] = 0.f; fpi[k] = 0.f; }
#pragma unroll
    for (int l = 0; l < 12; ++l) {
#pragma unroll
        for (int k = 0; k < 13; ++k) {
            const int t = (k * l) % 24;
            fpr[k] += xnr[l] * s_c[t];
            fpi[k] -= xnr[l] * s_s[t];
        }
    }

    // top-6 of (f.re+U)^2+(f.im+U)^2 descending, f[o]=fp[2o]
    float a7[7];
#pragma unroll
    for (int o2 = 0; o2 < 7; ++o2) {
        float ar = fpr[2 * o2] + 1e-6f, ai = fpi[2 * o2] + 1e-6f;
        a7[o2] = ar * ar + ai * ai;
    }
#pragma unroll
    for (int pss = 0; pss < 6; ++pss)
#pragma unroll
        for (int j = 0; j < 6; ++j) {
            float hi = fmaxf(a7[j], a7[j + 1]);
            float lo = fminf(a7[j], a7[j + 1]);
            a7[j] = hi; a7[j + 1] = lo;
        }

    float p7[7];
#pragma unroll
    for (int o2 = 0; o2 < 7; ++o2) {
        float pr = 0.f, pi = 0.f;
#pragma unroll
        for (int k = 0; k < 13; ++k) {
            const float wr = s_wr[o2 * 19 + k], wi = s_wi[o2 * 19 + k];
            pr += fpr[k] * wr - fpi[k] * wi;
            pi += fpr[k] * wi + fpi[k] * wr;
        }
#pragma unroll
        for (int k = 0; k < 6; ++k) {
            const float wr = s_wr[o2 * 19 + 13 + k], wi = s_wi[o2 * 19 + 13 + k];
            pr += a7[k] * wr;
            pi += a7[k] * wi;
        }
        p7[o2] = pr * pr + pi * pi;
    }

    float m7[7], ex[7], sm[7];
#pragma unroll
    for (int o2 = 0; o2 < 7; ++o2) m7[o2] = p7[o2];
    red_max_h<7>(m7, sred, htid, half);
#pragma unroll
    for (int o2 = 0; o2 < 7; ++o2) { ex[o2] = __expf(p7[o2] - m7[o2]); sm[o2] = ex[o2]; }
    red_sum_h<7>(sm, sred, htid, half);

    float gr[7], gi[7];
#pragma unroll
    for (int o2 = 0; o2 < 7; ++o2) {
        const float wf = ex[o2] / sm[o2];
        gr[o2] = wf * fpr[2 * o2];
        gi[o2] = wf * fpi[2 * o2];
    }

    __bf16* xfp = xfq_bf + (size_t)row * 1536 + htid;
#pragma unroll
    for (int l = 0; l < 12; ++l) {
        float val = gr[0] + ((l & 1) ? -gr[6] : gr[6]);
#pragma unroll
        for (int o2 = 1; o2 < 6; ++o2) {
            const int t = (2 * o2 * l) % 24;
            val += 2.0f * (gr[o2] * s_c[t] - gi[o2] * s_s[t]);
        }
        xfp[l * 128] = (__bf16)(val * (1.0f / 12.0f));
    }
    // last red_sum_h barrier guarantees sxn visible to all waves

    // ---- phase B: in_proj (2 m-tiles x 16 n-tiles over 4 waves) ----
    const int wave = tid >> 6, lane = tid & 63;
    const int lm = lane & 15, lq = lane >> 4;
    const int mw = wave & 1, nwv = wave >> 1;
    const __bf16* Wi = in_w_bf + (size_t)e * 256 * 128;
    bfx8 af[4];
#pragma unroll
    for (int kc = 0; kc < 4; ++kc)
        af[kc] = *(const bfx8*)(sxn + (mw * 16 + lm) * 136 + kc * 32 + lq * 8);

    f32x4 acc[8];
#pragma unroll
    for (int nt = 0; nt < 8; ++nt) acc[nt] = (f32x4){0.f, 0.f, 0.f, 0.f};
#pragma unroll
    for (int kc = 0; kc < 4; ++kc) {
        const int kb = kc * 32 + lq * 8;
#pragma unroll
        for (int nt = 0; nt < 8; ++nt) {
            bfx8 b = *(const bfx8*)(Wi + (size_t)(nwv * 128 + nt * 16 + lm) * 128 + kb);
            acc[nt] = MFMA16(af[kc], b, acc[nt]);
        }
    }
#pragma unroll
    for (int nt = 0; nt < 8; ++nt) {
        const int col = nwv * 128 + nt * 16 + lm;
        const float bias = in_b[e * 256 + col];
#pragma unroll
        for (int r = 0; r < 4; ++r) {
            const int m = mw * 16 + lq * 4 + r;
            if (m < 24) {
                const float vv = fsilu(acc[nt][r] + bias);
                if (col < 128) {
                    sxs[m * 136 + col] = (__bf16)vv;
                    xs_bf[(size_t)(m0g + m) * 128 + col] = (__bf16)vv;
                } else {
                    sz_bf[(size_t)(m0g + m) * 128 + (col - 128)] = (__bf16)vv;
                }
            }
        }
    }
    __syncthreads();

    // ---- phase C: x_proj (2 m-tiles x 12 n-tiles over 4 waves) ----
    const __bf16* Wx = x_w_bf + (size_t)e * 192 * 128;
    bfx8 ax[4];
#pragma unroll
    for (int kc = 0; kc < 4; ++kc)
        ax[kc] = *(const bfx8*)(sxs + (mw * 16 + lm) * 136 + kc * 32 + lq * 8);

    f32x4 xacc[6];
#pragma unroll
    for (int nt = 0; nt < 6; ++nt) xacc[nt] = (f32x4){0.f, 0.f, 0.f, 0.f};
#pragma unroll
    for (int kc = 0; kc < 4; ++kc) {
        const int kb = kc * 32 + lq * 8;
#pragma unroll
        for (int ntl = 0; ntl < 6; ++ntl) {
            const int nt = nwv * 6 + ntl;
            bfx8 b = *(const bfx8*)(Wx + (size_t)(nt * 16 + lm) * 128 + kb);
            xacc[ntl] = MFMA16(ax[kc], b, xacc[ntl]);
        }
    }
#pragma unroll
    for (int ntl = 0; ntl < 6; ++ntl) {
        const int col = (nwv * 6 + ntl) * 16 + lm;
#pragma unroll
        for (int r = 0; r < 4; ++r) {
            const int m = mw * 16 + lq * 4 + r;
            if (m < 24) {
                const float vv = xacc[ntl][r];
                if (col < 32) sdel[m * 40 + col] = (__bf16)vv;
                else if (col < 64) bcf32[(size_t)(m0g + m) * 32 + (col - 32)] = vv;
                else dpf[(size_t)(m0g + m) * 128 + (col - 64)] = (__bf16)vv;
            }
        }
    }
    __syncthreads();

    // ---- phase D: dt projection (2 m-tiles x 8 n-tiles over 4 waves) ----
    const __bf16* DW = dtw_bf + (size_t)e * 128 * 32;
    bfx8 ad = *(const bfx8*)(sdel + (mw * 16 + lm) * 40 + lq * 8);
    const f32x4 z4 = {0.f, 0.f, 0.f, 0.f};
#pragma unroll
    for (int ntl = 0; ntl < 4; ++ntl) {
        const int nt = nwv * 4 + ntl;
        bfx8 b = *(const bfx8*)(DW + (size_t)(nt * 16 + lm) * 32 + lq * 8);
        f32x4 dacc = MFMA16(ad, b, z4);
        const int col = nt * 16 + lm;
        const float bias = dt_b[e * 128 + col];
#pragma unroll
        for (int r = 0; r < 4; ++r) {
            const int m = mw * 16 + lq * 4 + r;
            if (m < 24)
                delta_bf[(size_t)(m0g + m) * 128 + col] = (__bf16)fsoftplus(dacc[r] + bias);
        }
    }
}

// ---------------- K2: graph mixing, 96 batched MFMA GEMMs -> dmix bf16 ----------------
__global__ __launch_bounds__(256)
void gemm_gm(const __bf16* __restrict__ delta_bf, const __bf16* __restrict__ graphT_bf,
             __bf16* __restrict__ dmix_bf) {
    const int bl = blockIdx.x;
    const int b = bl / 12, l = bl - b * 12;
    const int tid = threadIdx.x;
    const int wave = tid >> 6, lane = tid & 63;
    const int lm = lane & 15, lq = lane >> 4;
    const int nbase = blockIdx.y * 64 + wave * 16;
    const int n0c = blockIdx.z * 64;
    const __bf16* Bp = graphT_bf + (size_t)bl * 16384;

    f32x4 acc[4];
#pragma unroll
    for (int nt = 0; nt < 4; ++nt) acc[nt] = (f32x4){0.f, 0.f, 0.f, 0.f};

    const int nodeA = min(nbase + lm, NODES - 1);
    const __bf16* Ap = delta_bf + ((size_t)(b * NODES + nodeA) * 12 + l) * 128;

#pragma unroll
    for (int kc = 0; kc < 4; ++kc) {
        const int kb = kc * 32 + lq * 8;
        bfx8 a = *(const bfx8*)(Ap + kb);
#pragma unroll
        for (int nt = 0; nt < 4; ++nt) {
            bfx8 bb = *(const bfx8*)(Bp + (size_t)(n0c + nt * 16 + lm) * 128 + kb);
            acc[nt] = MFMA16(a, bb, acc[nt]);
        }
    }

#pragma unroll
    for (int nt = 0; nt < 4; ++nt)
#pragma unroll
        for (int r = 0; r < 4; ++r) {
            const int node = nbase + lq * 4 + r;
            if (node < NODES)
                dmix_bf[((size_t)(b * NODES + node) * 12 + l) * 128 + n0c + nt * 16 + lm]
                    = (__bf16)acc[nt][r];
        }
}

// ---------------- K3: SSM scan + gate + out_proj + residual (+final silu) ----------------
// grid (2456) x 128
__global__ __launch_bounds__(128)
void k_scanout(const __bf16* __restrict__ dmix_bf, const __bf16* __restrict__ xs_bf,
               const __bf16* __restrict__ sz_bf, const __bf16* __restrict__ xfq_bf,
               const float* __restrict__ bcf32, const __bf16* __restrict__ dpf,
               const float* __restrict__ A_log, const __bf16* __restrict__ out_w_bf,
               const float* __restrict__ out_b, const float* __restrict__ blk_w,
               const float* __restrict__ blk_b, const float* __restrict__ xprev,
               float* __restrict__ xout, int e, int last) {
    __shared__ __bf16 s_out[16 * 136];
    __shared__ float sBC[384];
    const int row = blockIdx.x, tid = threadIdx.x;
    for (int i = tid; i < 384; i += 128) sBC[i] = bcf32[(size_t)row * 384 + i];
    float As[16];
#pragma unroll
    for (int s = 0; s < 16; ++s) As[s] = -__expf(A_log[e * 16 + s]);
#pragma unroll
    for (int r = 12; r < 16; ++r) s_out[r * 136 + tid] = (__bf16)0.f;
    __syncthreads();

    const __bf16* dmp = dmix_bf + (size_t)row * 1536 + tid;
    const __bf16* xsp = xs_bf + (size_t)row * 1536 + tid;
    const __bf16* szp = sz_bf + (size_t)row * 1536 + tid;
    const __bf16* xfp = xfq_bf + (size_t)row * 1536 + tid;
    const __bf16* dpp = dpf + (size_t)row * 1536 + tid;

    float h[16];
#pragma unroll
    for (int s = 0; s < 16; ++s) h[s] = 0.f;
#pragma unroll
    for (int l = 0; l < 12; ++l) {
        const float dl = (float)dmp[l * 128];
        const float xv = (float)xsp[l * 128];
        const float Dp = (float)dpp[l * 128];
        const float dlx = dl * xv;
        float y = 0.f;
#pragma unroll
        for (int s = 0; s < 16; ++s) {
            h[s] = __expf(dl * As[s]) * h[s] + sBC[l * 32 + s] * dlx;
            y += h[s] * sBC[l * 32 + 16 + s];
        }
        y += Dp * xv;
        const float g = y * (float)szp[l * 128] * (float)xfp[l * 128];
        s_out[l * 136 + tid] = (__bf16)g;
    }
    __syncthreads();

    // out_proj: N=128 split 64/64 by wave
    const int wave = tid >> 6, lane = tid & 63;
    const int lm = lane & 15, lq = lane >> 4;
    const __bf16* Wo = out_w_bf + (size_t)e * 16384;
    bfx8 a[4];
#pragma unroll
    for (int kc = 0; kc < 4; ++kc)
        a[kc] = *(const bfx8*)(s_out + lm * 136 + kc * 32 + lq * 8);

    f32x4 acc[4];
#pragma unroll
    for (int nt = 0; nt < 4; ++nt) acc[nt] = (f32x4){0.f, 0.f, 0.f, 0.f};
#pragma unroll
    for (int kc = 0; kc < 4; ++kc) {
        const int kb = kc * 32 + lq * 8;
#pragma unroll
        for (int nt = 0; nt < 4; ++nt) {
            bfx8 b = *(const bfx8*)(Wo + (size_t)(wave * 64 + nt * 16 + lm) * 128 + kb);
            acc[nt] = MFMA16(a[kc], b, acc[nt]);
        }
    }

    const float bw = blk_w[e], bb = blk_b[e];
#pragma unroll
    for (int nt = 0; nt < 4; ++nt) {
        const int col = wave * 64 + nt * 16 + lm;
        const float ob = out_b[e * 128 + col];
#pragma unroll
        for (int r = 0; r < 4; ++r) {
            const int m = lq * 4 + r;
            if (m < 12) {
                const size_t gi = ((size_t)row * 12 + m) * 128 + col;
                float v = bw * (acc[nt][r] + ob) + bb + xprev[gi];
                if (last) v = fsilu(v);
                xout[gi] = v;
            }
        }
    }
}

extern "C" void kernel_launch(void* const* d_in, const int* in_sizes, int n_in,
                              void* d_out, int out_size, void* d_ws, size_t ws_size,
                              hipStream_t stream) {
    (void)in_sizes; (void)n_in; (void)out_size; (void)ws_size;
    const float* x_in   = (const float*)d_in[0];
    const float* graph  = (const float*)d_in[1];
    const float* in_w   = (const float*)d_in[2];
    const float* in_b   = (const float*)d_in[3];
    const float* x_w    = (const float*)d_in[4];
    const float* dt_w   = (const float*)d_in[5];
    const float* dt_b   = (const float*)d_in[6];
    const float* A_log  = (const float*)d_in[7];
    const float* out_w  = (const float*)d_in[8];
    const float* out_b  = (const float*)d_in[9];
    const float* fw_r   = (const float*)d_in[10];
    const float* fw_i   = (const float*)d_in[11];
    const float* norm_w = (const float*)d_in[12];
    const float* blk_w  = (const float*)d_in[13];
    const float* blk_b  = (const float*)d_in[14];
    float* out = (float*)d_out;

    float* ws = (float*)d_ws;
    size_t o = 0;
    __bf16* in_w_bf   = (__bf16*)(ws + o); o += 131072 / 2;
    __bf16* x_w_bf    = (__bf16*)(ws + o); o += 98304 / 2;
    __bf16* out_w_bf  = (__bf16*)(ws + o); o += 65536 / 2;
    __bf16* dtw_bf    = (__bf16*)(ws + o); o += 65536 / 2;
    __bf16* graphT_bf = (__bf16*)(ws + o); o += 1572864 / 2;
    const size_t NE = (size_t)MROWS * 128;            // 3,772,416 elements
    __bf16* xfq_bf   = (__bf16*)(ws + o); o += NE / 2;
    __bf16* xs_bf    = (__bf16*)(ws + o); o += NE / 2;
    __bf16* sz_bf    = (__bf16*)(ws + o); o += NE / 2;
    __bf16* delta_bf = (__bf16*)(ws + o); o += NE / 2;
    __bf16* dpf      = (__bf16*)(ws + o); o += NE / 2;
    __bf16* dmix_bf  = (__bf16*)(ws + o); o += NE / 2;
    float*  bcf32    = ws + o;            o += (size_t)MROWS * 32;

    hipLaunchKernelGGL(k_convert, dim3(7552), dim3(256), 0, stream,
                       in_w, x_w, out_w, dt_w, graph,
                       in_w_bf, x_w_bf, out_w_bf, dtw_bf, graphT_bf);

    for (int e = 0; e < 4; ++e) {
        const float* xcur = (e == 0) ? x_in : (const float*)out;
        const int last = (e == 3) ? 1 : 0;
        hipLaunchKernelGGL(k_fiq, dim3(BN / 2), dim3(256), 0, stream,
                           xcur, norm_w, fw_r, fw_i, in_w_bf, in_b,
                           x_w_bf, dtw_bf, dt_b,
                           xfq_bf, xs_bf, sz_bf, bcf32, dpf, delta_bf, e);
        hipLaunchKernelGGL(gemm_gm, dim3(96, 5, 2), dim3(256), 0, stream,
                           delta_bf, graphT_bf, dmix_bf);
        hipLaunchKernelGGL(k_scanout, dim3(BN), dim3(128), 0, stream,
                           dmix_bf, xs_bf, sz_bf, xfq_bf, bcf32, dpf, A_log,
                           out_w_bf, out_b, blk_w, blk_b, xcur, out, e, last);
    }
}

// Round 10
// 488.091 us; speedup vs baseline: 1.0896x; 1.0896x over previous
//
#include <hip/hip_runtime.h>
#include <math.h>

#define BN    2456
#define LSEQ  12
#define DM    128
#define NODES 307
#define MROWS 29472   // BN * LSEQ

typedef __bf16 bfx8 __attribute__((ext_vector_type(8)));
typedef float  f32x4 __attribute__((ext_vector_type(4)));

#define MFMA16(a, b, c) __builtin_amdgcn_mfma_f32_16x16x32_bf16(a, b, c, 0, 0, 0)

__device__ __forceinline__ float fsilu(float v)     { return v / (1.0f + __expf(-v)); }
__device__ __forceinline__ float fsoftplus(float x) { return fmaxf(x, 0.f) + __logf(1.0f + __expf(-fabsf(x))); }

// ---------------- K0: convert weights to bf16 once per call ----------------
__global__ __launch_bounds__(256)
void k_convert(const float* __restrict__ in_w, const float* __restrict__ x_w,
               const float* __restrict__ out_w, const float* __restrict__ dt_w,
               const float* __restrict__ graph,
               __bf16* __restrict__ in_w_bf, __bf16* __restrict__ x_w_bf,
               __bf16* __restrict__ out_w_bf, __bf16* __restrict__ dtw_bf,
               __bf16* __restrict__ graphT_bf) {
    int idx = blockIdx.x * 256 + threadIdx.x;
    if (idx < 131072) { in_w_bf[idx] = (__bf16)in_w[idx]; return; }
    idx -= 131072;
    if (idx < 98304) { x_w_bf[idx] = (__bf16)x_w[idx]; return; }
    idx -= 98304;
    if (idx < 65536) { out_w_bf[idx] = (__bf16)out_w[idx]; return; }
    idx -= 65536;
    if (idx < 65536) { dtw_bf[idx] = (__bf16)dt_w[idx]; return; }
    idx -= 65536;
    if (idx < 1572864) {
        int bl = idx >> 14, r = idx & 16383;
        int d = r >> 7, a = r & 127;
        graphT_bf[(size_t)bl * 16384 + a * 128 + d] = (__bf16)graph[idx];
    }
}

// ---------------- block reductions over 128 threads (2 waves) ----------------
template <int N>
__device__ __forceinline__ void red_sum128(float* v, float* sred, int tid) {
#pragma unroll
    for (int off = 32; off; off >>= 1)
#pragma unroll
        for (int i = 0; i < N; ++i) v[i] += __shfl_xor(v[i], off, 64);
    if ((tid & 63) == 0) {
#pragma unroll
        for (int i = 0; i < N; ++i) sred[(tid >> 6) * N + i] = v[i];
    }
    __syncthreads();
#pragma unroll
    for (int i = 0; i < N; ++i) v[i] = sred[i] + sred[N + i];
    __syncthreads();
}

template <int N>
__device__ __forceinline__ void red_max128(float* v, float* sred, int tid) {
#pragma unroll
    for (int off = 32; off; off >>= 1)
#pragma unroll
        for (int i = 0; i < N; ++i) v[i] = fmaxf(v[i], __shfl_xor(v[i], off, 64));
    if ((tid & 63) == 0) {
#pragma unroll
        for (int i = 0; i < N; ++i) sred[(tid >> 6) * N + i] = v[i];
    }
    __syncthreads();
#pragma unroll
    for (int i = 0; i < N; ++i) v[i] = fmaxf(sred[i], sred[N + i]);
    __syncthreads();
}

// ---------------- K1: standalone rmsnorm + freq gating -> xn_bf, xfq_bf ----------------
// grid (2456) x 128
__global__ __launch_bounds__(128)
void k_freq(const float* __restrict__ xcur, const float* __restrict__ norm_w,
            const float* __restrict__ fw_r, const float* __restrict__ fw_i,
            __bf16* __restrict__ xn_bf, __bf16* __restrict__ xfq_bf, int e) {
    __shared__ float s_c[24], s_s[24], s_wr[133], s_wi[133];
    __shared__ float sred[24];
    const int row = blockIdx.x, tid = threadIdx.x;

    if (tid < 24) {
        float sv, cv;
        __sincosf(6.283185307179586f * (float)tid / 24.0f, &sv, &cv);
        s_c[tid] = cv; s_s[tid] = sv;
    }
    for (int i = tid; i < 133; i += 128) { s_wr[i] = fw_r[e * 133 + i]; s_wi[i] = fw_i[e * 133 + i]; }

    const float* xp = xcur + (size_t)row * 1536 + tid;
    float xv[12], v[12];
#pragma unroll
    for (int l = 0; l < 12; ++l) { xv[l] = xp[l * 128]; v[l] = xv[l] * xv[l]; }
    __syncthreads();                 // publish tables; order before sred use
    red_sum128<12>(v, sred, tid);

    const float nrmw = norm_w[e * DM + tid];
    float xnr[12];
#pragma unroll
    for (int l = 0; l < 12; ++l)
        xnr[l] = xv[l] * rsqrtf(v[l] * (1.0f / 128.0f) + 1e-5f) * nrmw;

    __bf16* xnp = xn_bf + (size_t)row * 1536 + tid;
#pragma unroll
    for (int l = 0; l < 12; ++l) xnp[l * 128] = (__bf16)xnr[l];

    // DFT n=24 padded, 13 bins; f (n=12) = fp at even bins (exact dedup)
    float fpr[13], fpi[13];
#pragma unroll
    for (int k = 0; k < 13; ++k) { fpr[k] = 0.f; fpi[k] = 0.f; }
#pragma unroll
    for (int l = 0; l < 12; ++l) {
#pragma unroll
        for (int k = 0; k < 13; ++k) {
            const int t = (k * l) % 24;
            fpr[k] += xnr[l] * s_c[t];
            fpi[k] -= xnr[l] * s_s[t];
        }
    }

    // top-6 of (f.re+U)^2+(f.im+U)^2 descending, f[o]=fp[2o]
    float a7[7];
#pragma unroll
    for (int o2 = 0; o2 < 7; ++o2) {
        float ar = fpr[2 * o2] + 1e-6f, ai = fpi[2 * o2] + 1e-6f;
        a7[o2] = ar * ar + ai * ai;
    }
#pragma unroll
    for (int pss = 0; pss < 6; ++pss)
#pragma unroll
        for (int j = 0; j < 6; ++j) {
            float hi = fmaxf(a7[j], a7[j + 1]);
            float lo = fminf(a7[j], a7[j + 1]);
            a7[j] = hi; a7[j + 1] = lo;
        }

    float p7[7];
#pragma unroll
    for (int o2 = 0; o2 < 7; ++o2) {
        float pr = 0.f, pi = 0.f;
#pragma unroll
        for (int k = 0; k < 13; ++k) {
            const float wr = s_wr[o2 * 19 + k], wi = s_wi[o2 * 19 + k];
            pr += fpr[k] * wr - fpi[k] * wi;
            pi += fpr[k] * wi + fpi[k] * wr;
        }
#pragma unroll
        for (int k = 0; k < 6; ++k) {
            const float wr = s_wr[o2 * 19 + 13 + k], wi = s_wi[o2 * 19 + 13 + k];
            pr += a7[k] * wr;
            pi += a7[k] * wi;
        }
        p7[o2] = pr * pr + pi * pi;
    }

    float m7[7], ex[7], sm[7];
#pragma unroll
    for (int o2 = 0; o2 < 7; ++o2) m7[o2] = p7[o2];
    red_max128<7>(m7, sred, tid);
#pragma unroll
    for (int o2 = 0; o2 < 7; ++o2) { ex[o2] = __expf(p7[o2] - m7[o2]); sm[o2] = ex[o2]; }
    red_sum128<7>(sm, sred, tid);

    float gr[7], gi[7];
#pragma unroll
    for (int o2 = 0; o2 < 7; ++o2) {
        const float wf = ex[o2] / sm[o2];
        gr[o2] = wf * fpr[2 * o2];
        gi[o2] = wf * fpi[2 * o2];
    }

    __bf16* xfp = xfq_bf + (size_t)row * 1536 + tid;
#pragma unroll
    for (int l = 0; l < 12; ++l) {
        float val = gr[0] + ((l & 1) ? -gr[6] : gr[6]);
#pragma unroll
        for (int o2 = 1; o2 < 6; ++o2) {
            const int t = (2 * o2 * l) % 24;
            val += 2.0f * (gr[o2] * s_c[t] - gi[o2] * s_s[t]);
        }
        xfp[l * 128] = (__bf16)(val * (1.0f / 12.0f));
    }
}

// ---------------- K2: fused in_proj + silu + x_proj + dt_proj ----------------
// grid (1842) x 256 (4 waves). 16 rows/block; n-tiles split across waves.
__global__ __launch_bounds__(256)
void gemm_inxp(const __bf16* __restrict__ xn_bf, const __bf16* __restrict__ in_w_bf,
               const float* __restrict__ in_b, const __bf16* __restrict__ x_w_bf,
               const __bf16* __restrict__ dtw_bf, const float* __restrict__ dt_b,
               __bf16* __restrict__ xs_bf, __bf16* __restrict__ sz_bf,
               float* __restrict__ bcf32, __bf16* __restrict__ dpf,
               __bf16* __restrict__ delta_bf, int e) {
    __shared__ __bf16 sxs[16 * 136];
    __shared__ __bf16 sdel[16 * 40];
    const int tid = threadIdx.x;
    const int wave = tid >> 6, lane = tid & 63;
    const int lm = lane & 15, lq = lane >> 4;
    const int m0g = blockIdx.x * 16;

    // ---- phase 1: in_proj, 16 n-tiles split 4/wave ----
    const __bf16* Wi = in_w_bf + (size_t)e * 256 * 128;
    bfx8 af[4];
#pragma unroll
    for (int kc = 0; kc < 4; ++kc)
        af[kc] = *(const bfx8*)(xn_bf + (size_t)(m0g + lm) * 128 + kc * 32 + lq * 8);

    f32x4 acc[4];
#pragma unroll
    for (int nt = 0; nt < 4; ++nt) acc[nt] = (f32x4){0.f, 0.f, 0.f, 0.f};
#pragma unroll
    for (int kc = 0; kc < 4; ++kc) {
        const int kb = kc * 32 + lq * 8;
#pragma unroll
        for (int ntl = 0; ntl < 4; ++ntl) {
            bfx8 b = *(const bfx8*)(Wi + (size_t)(wave * 64 + ntl * 16 + lm) * 128 + kb);
            acc[ntl] = MFMA16(af[kc], b, acc[ntl]);
        }
    }
#pragma unroll
    for (int ntl = 0; ntl < 4; ++ntl) {
        const int col = wave * 64 + ntl * 16 + lm;
        const float bias = in_b[e * 256 + col];
#pragma unroll
        for (int r = 0; r < 4; ++r) {
            const int rl = lq * 4 + r;
            const float v = fsilu(acc[ntl][r] + bias);
            if (col < 128) {
                sxs[rl * 136 + col] = (__bf16)v;
                xs_bf[(size_t)(m0g + rl) * 128 + col] = (__bf16)v;
            } else {
                sz_bf[(size_t)(m0g + rl) * 128 + (col - 128)] = (__bf16)v;
            }
        }
    }
    __syncthreads();

    // ---- phase 2: x_proj, 12 n-tiles split 3/wave, A from LDS ----
    const __bf16* Wx = x_w_bf + (size_t)e * 192 * 128;
    bfx8 ax[4];
#pragma unroll
    for (int kc = 0; kc < 4; ++kc)
        ax[kc] = *(const bfx8*)(sxs + lm * 136 + kc * 32 + lq * 8);

    f32x4 xacc[3];
#pragma unroll
    for (int nt = 0; nt < 3; ++nt) xacc[nt] = (f32x4){0.f, 0.f, 0.f, 0.f};
#pragma unroll
    for (int kc = 0; kc < 4; ++kc) {
        const int kb = kc * 32 + lq * 8;
#pragma unroll
        for (int ntl = 0; ntl < 3; ++ntl) {
            bfx8 b = *(const bfx8*)(Wx + (size_t)((wave * 3 + ntl) * 16 + lm) * 128 + kb);
            xacc[ntl] = MFMA16(ax[kc], b, xacc[ntl]);
        }
    }
#pragma unroll
    for (int ntl = 0; ntl < 3; ++ntl) {
        const int col = (wave * 3 + ntl) * 16 + lm;
#pragma unroll
        for (int r = 0; r < 4; ++r) {
            const int rl = lq * 4 + r;
            const float v = xacc[ntl][r];
            if (col < 32) sdel[rl * 40 + col] = (__bf16)v;
            else if (col < 64) bcf32[(size_t)(m0g + rl) * 32 + (col - 32)] = v;
            else dpf[(size_t)(m0g + rl) * 128 + (col - 64)] = (__bf16)v;
        }
    }
    __syncthreads();

    // ---- phase 3: dt projection (K=32), 8 n-tiles split 2/wave ----
    const __bf16* DW = dtw_bf + (size_t)e * 128 * 32;
    bfx8 ad = *(const bfx8*)(sdel + lm * 40 + lq * 8);
    const f32x4 z4 = {0.f, 0.f, 0.f, 0.f};
#pragma unroll
    for (int ntl = 0; ntl < 2; ++ntl) {
        const int nt = wave * 2 + ntl;
        bfx8 b = *(const bfx8*)(DW + (size_t)(nt * 16 + lm) * 32 + lq * 8);
        f32x4 dacc = MFMA16(ad, b, z4);
        const int col = nt * 16 + lm;
        const float bias = dt_b[e * 128 + col];
#pragma unroll
        for (int r = 0; r < 4; ++r) {
            const int m = m0g + lq * 4 + r;
            delta_bf[(size_t)m * 128 + col] = (__bf16)fsoftplus(dacc[r] + bias);
        }
    }
}

// ---------------- K3: graph mixing, 96 batched MFMA GEMMs -> dmix bf16 ----------------
__global__ __launch_bounds__(256)
void gemm_gm(const __bf16* __restrict__ delta_bf, const __bf16* __restrict__ graphT_bf,
             __bf16* __restrict__ dmix_bf) {
    const int bl = blockIdx.x;
    const int b = bl / 12, l = bl - b * 12;
    const int tid = threadIdx.x;
    const int wave = tid >> 6, lane = tid & 63;
    const int lm = lane & 15, lq = lane >> 4;
    const int nbase = blockIdx.y * 64 + wave * 16;
    const int n0c = blockIdx.z * 64;
    const __bf16* Bp = graphT_bf + (size_t)bl * 16384;

    f32x4 acc[4];
#pragma unroll
    for (int nt = 0; nt < 4; ++nt) acc[nt] = (f32x4){0.f, 0.f, 0.f, 0.f};

    const int nodeA = min(nbase + lm, NODES - 1);
    const __bf16* Ap = delta_bf + ((size_t)(b * NODES + nodeA) * 12 + l) * 128;

#pragma unroll
    for (int kc = 0; kc < 4; ++kc) {
        const int kb = kc * 32 + lq * 8;
        bfx8 a = *(const bfx8*)(Ap + kb);
#pragma unroll
        for (int nt = 0; nt < 4; ++nt) {
            bfx8 bb = *(const bfx8*)(Bp + (size_t)(n0c + nt * 16 + lm) * 128 + kb);
            acc[nt] = MFMA16(a, bb, acc[nt]);
        }
    }

#pragma unroll
    for (int nt = 0; nt < 4; ++nt)
#pragma unroll
        for (int r = 0; r < 4; ++r) {
            const int node = nbase + lq * 4 + r;
            if (node < NODES)
                dmix_bf[((size_t)(b * NODES + node) * 12 + l) * 128 + n0c + nt * 16 + lm]
                    = (__bf16)acc[nt][r];
        }
}

// ---------------- K4: SSM scan + gate + out_proj + residual (+final silu) ----------------
// grid (2456) x 128
__global__ __launch_bounds__(128)
void k_scanout(const __bf16* __restrict__ dmix_bf, const __bf16* __restrict__ xs_bf,
               const __bf16* __restrict__ sz_bf, const __bf16* __restrict__ xfq_bf,
               const float* __restrict__ bcf32, const __bf16* __restrict__ dpf,
               const float* __restrict__ A_log, const __bf16* __restrict__ out_w_bf,
               const float* __restrict__ out_b, const float* __restrict__ blk_w,
               const float* __restrict__ blk_b, const float* __restrict__ xprev,
               float* __restrict__ xout, int e, int last) {
    __shared__ __bf16 s_out[16 * 136];
    __shared__ float sBC[384];
    const int row = blockIdx.x, tid = threadIdx.x;
    for (int i = tid; i < 384; i += 128) sBC[i] = bcf32[(size_t)row * 384 + i];
    float As[16];
#pragma unroll
    for (int s = 0; s < 16; ++s) As[s] = -__expf(A_log[e * 16 + s]);
#pragma unroll
    for (int r = 12; r < 16; ++r) s_out[r * 136 + tid] = (__bf16)0.f;
    __syncthreads();

    const __bf16* dmp = dmix_bf + (size_t)row * 1536 + tid;
    const __bf16* xsp = xs_bf + (size_t)row * 1536 + tid;
    const __bf16* szp = sz_bf + (size_t)row * 1536 + tid;
    const __bf16* xfp = xfq_bf + (size_t)row * 1536 + tid;
    const __bf16* dpp = dpf + (size_t)row * 1536 + tid;

    float h[16];
#pragma unroll
    for (int s = 0; s < 16; ++s) h[s] = 0.f;
#pragma unroll
    for (int l = 0; l < 12; ++l) {
        const float dl = (float)dmp[l * 128];
        const float xv = (float)xsp[l * 128];
        const float Dp = (float)dpp[l * 128];
        const float dlx = dl * xv;
        float y = 0.f;
#pragma unroll
        for (int s = 0; s < 16; ++s) {
            h[s] = __expf(dl * As[s]) * h[s] + sBC[l * 32 + s] * dlx;
            y += h[s] * sBC[l * 32 + 16 + s];
        }
        y += Dp * xv;
        const float g = y * (float)szp[l * 128] * (float)xfp[l * 128];
        s_out[l * 136 + tid] = (__bf16)g;
    }
    __syncthreads();

    // out_proj: N=128 split 64/64 by wave
    const int wave = tid >> 6, lane = tid & 63;
    const int lm = lane & 15, lq = lane >> 4;
    const __bf16* Wo = out_w_bf + (size_t)e * 16384;
    bfx8 a[4];
#pragma unroll
    for (int kc = 0; kc < 4; ++kc)
        a[kc] = *(const bfx8*)(s_out + lm * 136 + kc * 32 + lq * 8);

    f32x4 acc[4];
#pragma unroll
    for (int nt = 0; nt < 4; ++nt) acc[nt] = (f32x4){0.f, 0.f, 0.f, 0.f};
#pragma unroll
    for (int kc = 0; kc < 4; ++kc) {
        const int kb = kc * 32 + lq * 8;
#pragma unroll
        for (int nt = 0; nt < 4; ++nt) {
            bfx8 b = *(const bfx8*)(Wo + (size_t)(wave * 64 + nt * 16 + lm) * 128 + kb);
            acc[nt] = MFMA16(a[kc], b, acc[nt]);
        }
    }

    const float bw = blk_w[e], bb = blk_b[e];
#pragma unroll
    for (int nt = 0; nt < 4; ++nt) {
        const int col = wave * 64 + nt * 16 + lm;
        const float ob = out_b[e * 128 + col];
#pragma unroll
        for (int r = 0; r < 4; ++r) {
            const int m = lq * 4 + r;
            if (m < 12) {
                const size_t gi = ((size_t)row * 12 + m) * 128 + col;
                float v = bw * (acc[nt][r] + ob) + bb + xprev[gi];
                if (last) v = fsilu(v);
                xout[gi] = v;
            }
        }
    }
}

extern "C" void kernel_launch(void* const* d_in, const int* in_sizes, int n_in,
                              void* d_out, int out_size, void* d_ws, size_t ws_size,
                              hipStream_t stream) {
    (void)in_sizes; (void)n_in; (void)out_size; (void)ws_size;
    const float* x_in   = (const float*)d_in[0];
    const float* graph  = (const float*)d_in[1];
    const float* in_w   = (const float*)d_in[2];
    const float* in_b   = (const float*)d_in[3];
    const float* x_w    = (const float*)d_in[4];
    const float* dt_w   = (const float*)d_in[5];
    const float* dt_b   = (const float*)d_in[6];
    const float* A_log  = (const float*)d_in[7];
    const float* out_w  = (const float*)d_in[8];
    const float* out_b  = (const float*)d_in[9];
    const float* fw_r   = (const float*)d_in[10];
    const float* fw_i   = (const float*)d_in[11];
    const float* norm_w = (const float*)d_in[12];
    const float* blk_w  = (const float*)d_in[13];
    const float* blk_b  = (const float*)d_in[14];
    float* out = (float*)d_out;

    float* ws = (float*)d_ws;
    size_t o = 0;
    __bf16* in_w_bf   = (__bf16*)(ws + o); o += 131072 / 2;
    __bf16* x_w_bf    = (__bf16*)(ws + o); o += 98304 / 2;
    __bf16* out_w_bf  = (__bf16*)(ws + o); o += 65536 / 2;
    __bf16* dtw_bf    = (__bf16*)(ws + o); o += 65536 / 2;
    __bf16* graphT_bf = (__bf16*)(ws + o); o += 1572864 / 2;
    const size_t NE = (size_t)MROWS * 128;            // 3,772,416 elements
    __bf16* xn_bf    = (__bf16*)(ws + o); o += NE / 2;
    __bf16* xfq_bf   = (__bf16*)(ws + o); o += NE / 2;
    __bf16* xs_bf    = (__bf16*)(ws + o); o += NE / 2;
    __bf16* sz_bf    = (__bf16*)(ws + o); o += NE / 2;
    __bf16* delta_bf = (__bf16*)(ws + o); o += NE / 2;
    __bf16* dpf      = (__bf16*)(ws + o); o += NE / 2;
    __bf16* dmix_bf  = (__bf16*)(ws + o); o += NE / 2;
    float*  bcf32    = ws + o;            o += (size_t)MROWS * 32;

    hipLaunchKernelGGL(k_convert, dim3(7552), dim3(256), 0, stream,
                       in_w, x_w, out_w, dt_w, graph,
                       in_w_bf, x_w_bf, out_w_bf, dtw_bf, graphT_bf);

    for (int e = 0; e < 4; ++e) {
        const float* xcur = (e == 0) ? x_in : (const float*)out;
        const int last = (e == 3) ? 1 : 0;
        hipLaunchKernelGGL(k_freq, dim3(BN), dim3(128), 0, stream,
                           xcur, norm_w, fw_r, fw_i, xn_bf, xfq_bf, e);
        hipLaunchKernelGGL(gemm_inxp, dim3(1842), dim3(256), 0, stream,
                           xn_bf, in_w_bf, in_b, x_w_bf, dtw_bf, dt_b,
                           xs_bf, sz_bf, bcf32, dpf, delta_bf, e);
        hipLaunchKernelGGL(gemm_gm, dim3(96, 5, 2), dim3(256), 0, stream,
                           delta_bf, graphT_bf, dmix_bf);
        hipLaunchKernelGGL(k_scanout, dim3(BN), dim3(128), 0, stream,
                           dmix_bf, xs_bf, sz_bf, xfq_bf, bcf32, dpf, A_log,
                           out_w_bf, out_b, blk_w, blk_b, xcur, out, e, last);
    }
}

// Round 11
// 467.349 us; speedup vs baseline: 1.1379x; 1.0444x over previous
//
#include <hip/hip_runtime.h>
#include <math.h>

#define BN    2456
#define LSEQ  12
#define DM    128
#define NODES 307
#define MROWS 29472   // BN * LSEQ

typedef __bf16 bfx8 __attribute__((ext_vector_type(8)));
typedef float  f32x4 __attribute__((ext_vector_type(4)));

#define MFMA16(a, b, c) __builtin_amdgcn_mfma_f32_16x16x32_bf16(a, b, c, 0, 0, 0)

__device__ __forceinline__ float fsilu(float v)     { return v / (1.0f + __expf(-v)); }
__device__ __forceinline__ float fsoftplus(float x) { return fmaxf(x, 0.f) + __logf(1.0f + __expf(-fabsf(x))); }

// ---------------- K0: convert weights to bf16 once per call ----------------
__global__ __launch_bounds__(256)
void k_convert(const float* __restrict__ in_w, const float* __restrict__ x_w,
               const float* __restrict__ out_w, const float* __restrict__ dt_w,
               const float* __restrict__ graph,
               __bf16* __restrict__ in_w_bf, __bf16* __restrict__ x_w_bf,
               __bf16* __restrict__ out_w_bf, __bf16* __restrict__ dtw_bf,
               __bf16* __restrict__ graphT_bf) {
    int idx = blockIdx.x * 256 + threadIdx.x;
    if (idx < 131072) { in_w_bf[idx] = (__bf16)in_w[idx]; return; }
    idx -= 131072;
    if (idx < 98304) { x_w_bf[idx] = (__bf16)x_w[idx]; return; }
    idx -= 98304;
    if (idx < 65536) { out_w_bf[idx] = (__bf16)out_w[idx]; return; }
    idx -= 65536;
    if (idx < 65536) { dtw_bf[idx] = (__bf16)dt_w[idx]; return; }
    idx -= 65536;
    if (idx < 1572864) {
        int bl = idx >> 14, r = idx & 16383;
        int d = r >> 7, a = r & 127;
        graphT_bf[(size_t)bl * 16384 + a * 128 + d] = (__bf16)graph[idx];
    }
}

// ---------------- block reductions over 128 threads (2 waves) ----------------
template <int N>
__device__ __forceinline__ void red_sum128(float* v, float* sred, int tid) {
#pragma unroll
    for (int off = 32; off; off >>= 1)
#pragma unroll
        for (int i = 0; i < N; ++i) v[i] += __shfl_xor(v[i], off, 64);
    if ((tid & 63) == 0) {
#pragma unroll
        for (int i = 0; i < N; ++i) sred[(tid >> 6) * N + i] = v[i];
    }
    __syncthreads();
#pragma unroll
    for (int i = 0; i < N; ++i) v[i] = sred[i] + sred[N + i];
    __syncthreads();
}

template <int N>
__device__ __forceinline__ void red_max128(float* v, float* sred, int tid) {
#pragma unroll
    for (int off = 32; off; off >>= 1)
#pragma unroll
        for (int i = 0; i < N; ++i) v[i] = fmaxf(v[i], __shfl_xor(v[i], off, 64));
    if ((tid & 63) == 0) {
#pragma unroll
        for (int i = 0; i < N; ++i) sred[(tid >> 6) * N + i] = v[i];
    }
    __syncthreads();
#pragma unroll
    for (int i = 0; i < N; ++i) v[i] = fmaxf(sred[i], sred[N + i]);
    __syncthreads();
}

// ---------------- K1: rmsnorm + freq gating -> xn, xfq in [b][l][node][d] ----------------
// grid (2456) x 128
__global__ __launch_bounds__(128)
void k_freq(const float* __restrict__ xcur, const float* __restrict__ norm_w,
            const float* __restrict__ fw_r, const float* __restrict__ fw_i,
            __bf16* __restrict__ xn_bf, __bf16* __restrict__ xfq_bf, int e) {
    __shared__ float s_c[24], s_s[24], s_wr[133], s_wi[133];
    __shared__ float sred[24];
    const int row = blockIdx.x, tid = threadIdx.x;
    const int b = row / NODES, n = row - b * NODES;

    if (tid < 24) {
        float sv, cv;
        __sincosf(6.283185307179586f * (float)tid / 24.0f, &sv, &cv);
        s_c[tid] = cv; s_s[tid] = sv;
    }
    for (int i = tid; i < 133; i += 128) { s_wr[i] = fw_r[e * 133 + i]; s_wi[i] = fw_i[e * 133 + i]; }

    const float* xp = xcur + (size_t)row * 1536 + tid;
    float xv[12], v[12];
#pragma unroll
    for (int l = 0; l < 12; ++l) { xv[l] = xp[l * 128]; v[l] = xv[l] * xv[l]; }
    __syncthreads();                 // publish tables
    red_sum128<12>(v, sred, tid);

    const float nrmw = norm_w[e * DM + tid];
    float xnr[12];
#pragma unroll
    for (int l = 0; l < 12; ++l)
        xnr[l] = xv[l] * rsqrtf(v[l] * (1.0f / 128.0f) + 1e-5f) * nrmw;

#pragma unroll
    for (int l = 0; l < 12; ++l)
        xn_bf[((size_t)(b * 12 + l) * NODES + n) * 128 + tid] = (__bf16)xnr[l];

    // DFT n=24 padded, 13 bins; f (n=12) = fp at even bins (exact dedup)
    float fpr[13], fpi[13];
#pragma unroll
    for (int k = 0; k < 13; ++k) { fpr[k] = 0.f; fpi[k] = 0.f; }
#pragma unroll
    for (int l = 0; l < 12; ++l) {
#pragma unroll
        for (int k = 0; k < 13; ++k) {
            const int t = (k * l) % 24;
            fpr[k] += xnr[l] * s_c[t];
            fpi[k] -= xnr[l] * s_s[t];
        }
    }

    float a7[7];
#pragma unroll
    for (int o2 = 0; o2 < 7; ++o2) {
        float ar = fpr[2 * o2] + 1e-6f, ai = fpi[2 * o2] + 1e-6f;
        a7[o2] = ar * ar + ai * ai;
    }
#pragma unroll
    for (int pss = 0; pss < 6; ++pss)
#pragma unroll
        for (int j = 0; j < 6; ++j) {
            float hi = fmaxf(a7[j], a7[j + 1]);
            float lo = fminf(a7[j], a7[j + 1]);
            a7[j] = hi; a7[j + 1] = lo;
        }

    float p7[7];
#pragma unroll
    for (int o2 = 0; o2 < 7; ++o2) {
        float pr = 0.f, pi = 0.f;
#pragma unroll
        for (int k = 0; k < 13; ++k) {
            const float wr = s_wr[o2 * 19 + k], wi = s_wi[o2 * 19 + k];
            pr += fpr[k] * wr - fpi[k] * wi;
            pi += fpr[k] * wi + fpi[k] * wr;
        }
#pragma unroll
        for (int k = 0; k < 6; ++k) {
            const float wr = s_wr[o2 * 19 + 13 + k], wi = s_wi[o2 * 19 + 13 + k];
            pr += a7[k] * wr;
            pi += a7[k] * wi;
        }
        p7[o2] = pr * pr + pi * pi;
    }

    float m7[7], ex[7], sm[7];
#pragma unroll
    for (int o2 = 0; o2 < 7; ++o2) m7[o2] = p7[o2];
    red_max128<7>(m7, sred, tid);
#pragma unroll
    for (int o2 = 0; o2 < 7; ++o2) { ex[o2] = __expf(p7[o2] - m7[o2]); sm[o2] = ex[o2]; }
    red_sum128<7>(sm, sred, tid);

    float gr[7], gi[7];
#pragma unroll
    for (int o2 = 0; o2 < 7; ++o2) {
        const float wf = ex[o2] / sm[o2];
        gr[o2] = wf * fpr[2 * o2];
        gi[o2] = wf * fpi[2 * o2];
    }

#pragma unroll
    for (int l = 0; l < 12; ++l) {
        float val = gr[0] + ((l & 1) ? -gr[6] : gr[6]);
#pragma unroll
        for (int o2 = 1; o2 < 6; ++o2) {
            const int t = (2 * o2 * l) % 24;
            val += 2.0f * (gr[o2] * s_c[t] - gi[o2] * s_s[t]);
        }
        xfq_bf[((size_t)(b * 12 + l) * NODES + n) * 128 + tid] = (__bf16)(val * (1.0f / 12.0f));
    }
}

// ---------------- K2: fused in_proj + silu + x_proj + dt_proj + graph-mix ----------------
// grid (96, 20) x 256 (4 waves). block = (b,l) x 16-node tile; delta never leaves LDS.
__global__ __launch_bounds__(256)
void k_fused(const __bf16* __restrict__ xn_bf, const __bf16* __restrict__ in_w_bf,
             const float* __restrict__ in_b, const __bf16* __restrict__ x_w_bf,
             const __bf16* __restrict__ dtw_bf, const float* __restrict__ dt_b,
             const __bf16* __restrict__ graphT_bf,
             __bf16* __restrict__ xs_bf, __bf16* __restrict__ sz_bf,
             float* __restrict__ bcf32, __bf16* __restrict__ dpf,
             __bf16* __restrict__ dmix_bf, int e) {
    __shared__ __bf16 sxs[16 * 136];
    __shared__ __bf16 sdelta[16 * 136];
    __shared__ __bf16 sdel32[16 * 40];
    const int bl = blockIdx.x;
    const int n0 = blockIdx.y * 16;
    const int tid = threadIdx.x;
    const int wave = tid >> 6, lane = tid & 63;
    const int lm = lane & 15, lq = lane >> 4;
    const size_t rowbase = (size_t)bl * NODES + n0;

    // ---- phase 1: in_proj, 16 n-tiles split 4/wave ----
    const __bf16* Wi = in_w_bf + (size_t)e * 256 * 128;
    const size_t arow = (size_t)bl * NODES + min(n0 + lm, NODES - 1);
    bfx8 af[4];
#pragma unroll
    for (int kc = 0; kc < 4; ++kc)
        af[kc] = *(const bfx8*)(xn_bf + arow * 128 + kc * 32 + lq * 8);

    f32x4 acc[4];
#pragma unroll
    for (int nt = 0; nt < 4; ++nt) acc[nt] = (f32x4){0.f, 0.f, 0.f, 0.f};
#pragma unroll
    for (int kc = 0; kc < 4; ++kc) {
        const int kb = kc * 32 + lq * 8;
#pragma unroll
        for (int ntl = 0; ntl < 4; ++ntl) {
            bfx8 b = *(const bfx8*)(Wi + (size_t)(wave * 64 + ntl * 16 + lm) * 128 + kb);
            acc[ntl] = MFMA16(af[kc], b, acc[ntl]);
        }
    }
#pragma unroll
    for (int ntl = 0; ntl < 4; ++ntl) {
        const int col = wave * 64 + ntl * 16 + lm;
        const float bias = in_b[e * 256 + col];
#pragma unroll
        for (int r = 0; r < 4; ++r) {
            const int node = lq * 4 + r;
            const float v = fsilu(acc[ntl][r] + bias);
            const int ok = (n0 + node) < NODES;
            if (col < 128) {
                sxs[node * 136 + col] = (__bf16)v;
                if (ok) xs_bf[(rowbase + node) * 128 + col] = (__bf16)v;
            } else if (ok) {
                sz_bf[(rowbase + node) * 128 + (col - 128)] = (__bf16)v;
            }
        }
    }
    __syncthreads();

    // ---- phase 2: x_proj, 12 n-tiles split 3/wave, A from LDS ----
    const __bf16* Wx = x_w_bf + (size_t)e * 192 * 128;
    bfx8 ax[4];
#pragma unroll
    for (int kc = 0; kc < 4; ++kc)
        ax[kc] = *(const bfx8*)(sxs + lm * 136 + kc * 32 + lq * 8);

    f32x4 xacc[3];
#pragma unroll
    for (int nt = 0; nt < 3; ++nt) xacc[nt] = (f32x4){0.f, 0.f, 0.f, 0.f};
#pragma unroll
    for (int kc = 0; kc < 4; ++kc) {
        const int kb = kc * 32 + lq * 8;
#pragma unroll
        for (int ntl = 0; ntl < 3; ++ntl) {
            bfx8 b = *(const bfx8*)(Wx + (size_t)((wave * 3 + ntl) * 16 + lm) * 128 + kb);
            xacc[ntl] = MFMA16(ax[kc], b, xacc[ntl]);
        }
    }
#pragma unroll
    for (int ntl = 0; ntl < 3; ++ntl) {
        const int col = (wave * 3 + ntl) * 16 + lm;
#pragma unroll
        for (int r = 0; r < 4; ++r) {
            const int node = lq * 4 + r;
            const float v = xacc[ntl][r];
            const int ok = (n0 + node) < NODES;
            if (col < 32) sdel32[node * 40 + col] = (__bf16)v;
            else if (col < 64) { if (ok) bcf32[(rowbase + node) * 32 + (col - 32)] = v; }
            else if (ok) dpf[(rowbase + node) * 128 + (col - 64)] = (__bf16)v;
        }
    }
    __syncthreads();

    // ---- phase 3: dt projection (K=32), 8 n-tiles split 2/wave -> delta in LDS ----
    const __bf16* DW = dtw_bf + (size_t)e * 128 * 32;
    bfx8 ad = *(const bfx8*)(sdel32 + lm * 40 + lq * 8);
    const f32x4 z4 = {0.f, 0.f, 0.f, 0.f};
#pragma unroll
    for (int ntl = 0; ntl < 2; ++ntl) {
        const int nt = wave * 2 + ntl;
        bfx8 b = *(const bfx8*)(DW + (size_t)(nt * 16 + lm) * 32 + lq * 8);
        f32x4 dacc = MFMA16(ad, b, z4);
        const int col = nt * 16 + lm;
        const float bias = dt_b[e * 128 + col];
#pragma unroll
        for (int r = 0; r < 4; ++r) {
            const int node = lq * 4 + r;
            sdelta[node * 136 + col] = (__bf16)fsoftplus(dacc[r] + bias);
        }
    }
    __syncthreads();

    // ---- phase 4: graph mix, 8 n-tiles split 2/wave, B = G[b,l] from global ----
    const __bf16* Gp = graphT_bf + (size_t)bl * 16384;
    bfx8 ag[4];
#pragma unroll
    for (int kc = 0; kc < 4; ++kc)
        ag[kc] = *(const bfx8*)(sdelta + lm * 136 + kc * 32 + lq * 8);

#pragma unroll
    for (int ntl = 0; ntl < 2; ++ntl) {
        const int nt = wave * 2 + ntl;
        f32x4 gacc = z4;
#pragma unroll
        for (int kc = 0; kc < 4; ++kc) {
            const int kb = kc * 32 + lq * 8;
            bfx8 b = *(const bfx8*)(Gp + (size_t)(nt * 16 + lm) * 128 + kb);
            gacc = MFMA16(ag[kc], b, gacc);
        }
        const int col = nt * 16 + lm;
#pragma unroll
        for (int r = 0; r < 4; ++r) {
            const int node = lq * 4 + r;
            if ((n0 + node) < NODES)
                dmix_bf[(rowbase + node) * 128 + col] = (__bf16)gacc[r];
        }
    }
}

// ---------------- K3: SSM scan + gate + out_proj + residual (+final silu) ----------------
// grid (2456) x 128
__global__ __launch_bounds__(128)
void k_scanout(const __bf16* __restrict__ dmix_bf, const __bf16* __restrict__ xs_bf,
               const __bf16* __restrict__ sz_bf, const __bf16* __restrict__ xfq_bf,
               const float* __restrict__ bcf32, const __bf16* __restrict__ dpf,
               const float* __restrict__ A_log, const __bf16* __restrict__ out_w_bf,
               const float* __restrict__ out_b, const float* __restrict__ blk_w,
               const float* __restrict__ blk_b, const float* __restrict__ xprev,
               float* __restrict__ xout, int e, int last) {
    __shared__ __bf16 s_out[16 * 136];
    __shared__ float sBC[384];
    const int row = blockIdx.x, tid = threadIdx.x;
    const int b = row / NODES, n = row - b * NODES;
    for (int i = tid; i < 384; i += 128) {
        const int l = i >> 5, s = i & 31;
        sBC[i] = bcf32[((size_t)(b * 12 + l) * NODES + n) * 32 + s];
    }
    float As[16];
#pragma unroll
    for (int s = 0; s < 16; ++s) As[s] = -__expf(A_log[e * 16 + s]);
#pragma unroll
    for (int r = 12; r < 16; ++r) s_out[r * 136 + tid] = (__bf16)0.f;
    __syncthreads();

    float h[16];
#pragma unroll
    for (int s = 0; s < 16; ++s) h[s] = 0.f;
#pragma unroll
    for (int l = 0; l < 12; ++l) {
        const size_t base = ((size_t)(b * 12 + l) * NODES + n) * 128 + tid;
        const float dl = (float)dmix_bf[base];
        const float xv = (float)xs_bf[base];
        const float Dp = (float)dpf[base];
        const float dlx = dl * xv;
        float y = 0.f;
#pragma unroll
        for (int s = 0; s < 16; ++s) {
            h[s] = __expf(dl * As[s]) * h[s] + sBC[l * 32 + s] * dlx;
            y += h[s] * sBC[l * 32 + 16 + s];
        }
        y += Dp * xv;
        const float g = y * (float)sz_bf[base] * (float)xfq_bf[base];
        s_out[l * 136 + tid] = (__bf16)g;
    }
    __syncthreads();

    // out_proj: N=128 split 64/64 by wave
    const int wave = tid >> 6, lane = tid & 63;
    const int lm = lane & 15, lq = lane >> 4;
    const __bf16* Wo = out_w_bf + (size_t)e * 16384;
    bfx8 a[4];
#pragma unroll
    for (int kc = 0; kc < 4; ++kc)
        a[kc] = *(const bfx8*)(s_out + lm * 136 + kc * 32 + lq * 8);

    f32x4 acc[4];
#pragma unroll
    for (int nt = 0; nt < 4; ++nt) acc[nt] = (f32x4){0.f, 0.f, 0.f, 0.f};
#pragma unroll
    for (int kc = 0; kc < 4; ++kc) {
        const int kb = kc * 32 + lq * 8;
#pragma unroll
        for (int nt = 0; nt < 4; ++nt) {
            bfx8 b = *(const bfx8*)(Wo + (size_t)(wave * 64 + nt * 16 + lm) * 128 + kb);
            acc[nt] = MFMA16(a[kc], b, acc[nt]);
        }
    }

    const float bw = blk_w[e], bb = blk_b[e];
#pragma unroll
    for (int nt = 0; nt < 4; ++nt) {
        const int col = wave * 64 + nt * 16 + lm;
        const float ob = out_b[e * 128 + col];
#pragma unroll
        for (int r = 0; r < 4; ++r) {
            const int m = lq * 4 + r;
            if (m < 12) {
                const size_t gi = ((size_t)row * 12 + m) * 128 + col;
                float v = bw * (acc[nt][r] + ob) + bb + xprev[gi];
                if (last) v = fsilu(v);
                xout[gi] = v;
            }
        }
    }
}

extern "C" void kernel_launch(void* const* d_in, const int* in_sizes, int n_in,
                              void* d_out, int out_size, void* d_ws, size_t ws_size,
                              hipStream_t stream) {
    (void)in_sizes; (void)n_in; (void)out_size; (void)ws_size;
    const float* x_in   = (const float*)d_in[0];
    const float* graph  = (const float*)d_in[1];
    const float* in_w   = (const float*)d_in[2];
    const float* in_b   = (const float*)d_in[3];
    const float* x_w    = (const float*)d_in[4];
    const float* dt_w   = (const float*)d_in[5];
    const float* dt_b   = (const float*)d_in[6];
    const float* A_log  = (const float*)d_in[7];
    const float* out_w  = (const float*)d_in[8];
    const float* out_b  = (const float*)d_in[9];
    const float* fw_r   = (const float*)d_in[10];
    const float* fw_i   = (const float*)d_in[11];
    const float* norm_w = (const float*)d_in[12];
    const float* blk_w  = (const float*)d_in[13];
    const float* blk_b  = (const float*)d_in[14];
    float* out = (float*)d_out;

    float* ws = (float*)d_ws;
    size_t o = 0;
    __bf16* in_w_bf   = (__bf16*)(ws + o); o += 131072 / 2;
    __bf16* x_w_bf    = (__bf16*)(ws + o); o += 98304 / 2;
    __bf16* out_w_bf  = (__bf16*)(ws + o); o += 65536 / 2;
    __bf16* dtw_bf    = (__bf16*)(ws + o); o += 65536 / 2;
    __bf16* graphT_bf = (__bf16*)(ws + o); o += 1572864 / 2;
    const size_t NE = (size_t)MROWS * 128;            // 3,772,416 elements
    __bf16* xn_bf    = (__bf16*)(ws + o); o += NE / 2;
    __bf16* xfq_bf   = (__bf16*)(ws + o); o += NE / 2;
    __bf16* xs_bf    = (__bf16*)(ws + o); o += NE / 2;
    __bf16* sz_bf    = (__bf16*)(ws + o); o += NE / 2;
    __bf16* dpf      = (__bf16*)(ws + o); o += NE / 2;
    __bf16* dmix_bf  = (__bf16*)(ws + o); o += NE / 2;
    float*  bcf32    = ws + o;            o += (size_t)MROWS * 32;

    hipLaunchKernelGGL(k_convert, dim3(7552), dim3(256), 0, stream,
                       in_w, x_w, out_w, dt_w, graph,
                       in_w_bf, x_w_bf, out_w_bf, dtw_bf, graphT_bf);

    for (int e = 0; e < 4; ++e) {
        const float* xcur = (e == 0) ? x_in : (const float*)out;
        const int last = (e == 3) ? 1 : 0;
        hipLaunchKernelGGL(k_freq, dim3(BN), dim3(128), 0, stream,
                           xcur, norm_w, fw_r, fw_i, xn_bf, xfq_bf, e);
        hipLaunchKernelGGL(k_fused, dim3(96, 20), dim3(256), 0, stream,
                           xn_bf, in_w_bf, in_b, x_w_bf, dtw_bf, dt_b, graphT_bf,
                           xs_bf, sz_bf, bcf32, dpf, dmix_bf, e);
        hipLaunchKernelGGL(k_scanout, dim3(BN), dim3(128), 0, stream,
                           dmix_bf, xs_bf, sz_bf, xfq_bf, bcf32, dpf, A_log,
                           out_w_bf, out_b, blk_w, blk_b, xcur, out, e, last);
    }
}